// Round 5
// baseline (344.156 us; speedup 1.0000x reference)
//
#include <hip/hip_runtime.h>
#include <hip/hip_bf16.h>
#include <math.h>

typedef __hip_bfloat16 hbf16;
typedef __attribute__((ext_vector_type(8))) __bf16    bf16x8;
typedef __attribute__((ext_vector_type(4))) float     f32x4;
typedef __attribute__((ext_vector_type(4))) _Float16  f16x4;
typedef __attribute__((ext_vector_type(8))) unsigned short u16x8;

#define C_    1024
#define NTOK  256
#define NH    16
#define J3    3072

__device__ __forceinline__ unsigned short fbits(float v){
    return __builtin_bit_cast(unsigned short, __float2bfloat16(v));
}
__device__ __forceinline__ __bf16 to_bf(float v){
    return __builtin_bit_cast(__bf16, __float2bfloat16(v));
}

__device__ __forceinline__ void gload_lds16(const __bf16* g, __bf16* l) {
    __builtin_amdgcn_global_load_lds((const __attribute__((address_space(1))) void*)g,
                                     (__attribute__((address_space(3))) void*)l, 16, 0, 0);
}

// ---------------------------------------------------------------------------
// cvt both weight tensors in one launch. blocks [0,3072) -> w_qkv, rest -> w_lin
// ---------------------------------------------------------------------------
__global__ __launch_bounds__(256) void cvt_w(const float* __restrict__ wq,
                                             __bf16* __restrict__ wqo,
                                             const float* __restrict__ wl,
                                             __bf16* __restrict__ wlo) {
    const float* in; __bf16* out; int i;
    if (blockIdx.x < 3072) { in = wq; out = wqo; i = blockIdx.x * 256 + threadIdx.x; }
    else                   { in = wl; out = wlo; i = (blockIdx.x - 3072) * 256 + threadIdx.x; }
    float4 v = ((const float4*)in)[i];
    ushort4 u;
    u.x = fbits(v.x); u.y = fbits(v.y); u.z = fbits(v.z); u.w = fbits(v.w);
    ((ushort4*)out)[i] = u;
}

// ---------------------------------------------------------------------------
// xpose_x: X[64,1024,256] f32 -> Xt[b*256+s][k] bf16   (32x32 LDS tiles)
// ---------------------------------------------------------------------------
__global__ __launch_bounds__(256) void xpose_x(const float* __restrict__ X,
                                               __bf16* __restrict__ Xt) {
    __shared__ float t[32][36];
    const int b = blockIdx.z, k0 = blockIdx.y * 32, s0 = blockIdx.x * 32;
    const int tid = threadIdx.x;
    {
        int kl = tid >> 3, s4 = (tid & 7) * 4;
        float4 v = *(const float4*)(X + ((size_t)b << 18) + (size_t)(k0 + kl) * 256 + s0 + s4);
        t[kl][s4] = v.x; t[kl][s4 + 1] = v.y; t[kl][s4 + 2] = v.z; t[kl][s4 + 3] = v.w;
    }
    __syncthreads();
    {
        int sl = tid >> 3, k4 = (tid & 7) * 4;
        ushort4 u;
        u.x = fbits(t[k4][sl]); u.y = fbits(t[k4 + 1][sl]);
        u.z = fbits(t[k4 + 2][sl]); u.w = fbits(t[k4 + 3][sl]);
        *(ushort4*)(Xt + (size_t)(b * 256 + s0 + sl) * 1024 + k0 + k4) = u;
    }
}

// ---------------------------------------------------------------------------
// mfma_gemm<EPI>: C[m,n] = sum_k A[m,k]*B[n,k] (both k-contiguous bf16, K=1024)
// 128x128 tile, BK=64, 4 waves, 16x16x32 MFMA.  (unchanged from round 4)
// EPI=0: C -> bf16 row-major ldc=3072 (Y), LDS-transposed coalesced stores.
// EPI=1: A=Wl (m=oc), B=Ot (n=b*256+s): direct stores out[b][oc][s] = C + bias[oc].
// ---------------------------------------------------------------------------
template <int EPI>
__global__ __launch_bounds__(256) void mfma_gemm(const __bf16* __restrict__ A,
                                                 const __bf16* __restrict__ B,
                                                 void* __restrict__ Cout,
                                                 const float* __restrict__ bias) {
    __shared__ union __align__(16) {
        struct { __bf16 A[128 * 64]; __bf16 B[128 * 64]; } kl;
        __bf16 stY[128][136];
    } sm;

    const int tid  = threadIdx.x;
    const int wave = tid >> 6, lane = tid & 63;
    const int wm = wave & 1, wn = wave >> 1;
    const int m0 = blockIdx.x * 128, n0 = blockIdx.y * 128;

    const int srow = lane >> 3;
    const int lchunk = (lane & 7) ^ srow;

    f32x4 acc[4][4] = {};

    for (int kk = 0; kk < 1024; kk += 64) {
        #pragma unroll
        for (int g4 = 0; g4 < 4; ++g4) {
            const int g = g4 * 4 + wave;
            const int row = g * 8 + srow;
            gload_lds16(A + (((size_t)(m0 + row)) << 10) + kk + lchunk * 8,
                        &sm.kl.A[g * 512]);
            gload_lds16(B + (((size_t)(n0 + row)) << 10) + kk + lchunk * 8,
                        &sm.kl.B[g * 512]);
        }
        __syncthreads();

        #pragma unroll
        for (int t = 0; t < 2; ++t) {
            const int chunk = t * 4 + (lane >> 4);
            bf16x8 af[4], bf[4];
            #pragma unroll
            for (int mi = 0; mi < 4; ++mi) {
                int row = wm * 64 + mi * 16 + (lane & 15);
                af[mi] = *(const bf16x8*)&sm.kl.A[row * 64 + ((chunk ^ (row & 7)) << 3)];
            }
            #pragma unroll
            for (int ni = 0; ni < 4; ++ni) {
                int row = wn * 64 + ni * 16 + (lane & 15);
                bf[ni] = *(const bf16x8*)&sm.kl.B[row * 64 + ((chunk ^ (row & 7)) << 3)];
            }
            #pragma unroll
            for (int mi = 0; mi < 4; ++mi)
                #pragma unroll
                for (int ni = 0; ni < 4; ++ni)
                    acc[mi][ni] = __builtin_amdgcn_mfma_f32_16x16x32_bf16(
                        af[mi], bf[ni], acc[mi][ni], 0, 0, 0);
        }
        __syncthreads();
    }

    const int cl = lane & 15, rq = lane >> 4;

    if (EPI == 0) {
        __syncthreads();
        #pragma unroll
        for (int mi = 0; mi < 4; ++mi)
            #pragma unroll
            for (int ni = 0; ni < 4; ++ni) {
                int row = wm * 64 + mi * 16 + rq * 4;
                int col = wn * 64 + ni * 16 + cl;
                #pragma unroll
                for (int j = 0; j < 4; ++j)
                    sm.stY[row + j][col] = to_bf(acc[mi][ni][j]);
            }
        __syncthreads();
        __bf16* Y = (__bf16*)Cout;
        #pragma unroll
        for (int i = 0; i < 8; ++i) {
            int cid = tid + 256 * i;
            int r = cid >> 4, c8 = (cid & 15) * 8;
            *(bf16x8*)(Y + (size_t)(m0 + r) * 3072 + n0 + c8) =
                *(const bf16x8*)&sm.stY[r][c8];
        }
    } else {
        float* out = (float*)Cout;
        float bia[4][4];
        const int rbase = m0 + wm * 64 + rq * 4;
        #pragma unroll
        for (int mi = 0; mi < 4; ++mi)
            #pragma unroll
            for (int j = 0; j < 4; ++j) bia[mi][j] = bias[rbase + mi * 16 + j];
        const int nbase = n0 + wn * 64 + cl;
        #pragma unroll
        for (int mi = 0; mi < 4; ++mi)
            #pragma unroll
            for (int ni = 0; ni < 4; ++ni) {
                int nn = nbase + ni * 16;
                size_t base = ((size_t)(nn >> 8) << 18) + (nn & 255);
                #pragma unroll
                for (int j = 0; j < 4; ++j) {
                    int oc = rbase + mi * 16 + j;
                    out[base + ((size_t)oc << 8)] = acc[mi][ni][j] + bia[mi][j];
                }
            }
    }
}

// ---------------------------------------------------------------------------
// attn_mfma: 8 waves/block (512 thr), one token per wave.
// Register-lean: q processed fully, then k (peak live ~100 VGPR; lb 512 -> cap 256).
// Output staged via LDS (72B-padded rows, XOR slot swizzle) -> full-line stores.
// ---------------------------------------------------------------------------
__global__ __launch_bounds__(512) void attn_mfma(const __bf16* __restrict__ Y,
                                                 __bf16* __restrict__ Ot) {
    __shared__ union __align__(16) {
        __bf16  v[8][1024];       // per-wave v[16 h][64 e]   (16 KB)
        ushort4 ost[256][9];      // [s][slot 0..7 + pad]     (18 KB)
    } sm;

    const int tid  = threadIdx.x;
    const int wave = tid >> 6, lane = tid & 63;
    const int bb = blockIdx.x >> 5;
    const int n0 = (blockIdx.x & 31) * 8;
    const int n  = n0 + wave;
    const int quad = lane >> 4, m = lane & 15;
    const __bf16* Yt = Y + (size_t)(bb * 256 + n) * J3;

    // ---- stage v[16][64] -> LDS (2 wave-level 16B DMA instrs) ----
    #pragma unroll
    for (int p = 0; p < 2; ++p) {
        const int h = p * 8 + (lane >> 3), part = lane & 7;
        gload_lds16(Yt + h * 192 + 128 + part * 8, &sm.v[wave][p * 512]);
    }

    // ---- RoPE trig (shared by q and k): d = quad*8 + j ----
    const float fn = (float)n;
    float sn[8], cn[8];
    #pragma unroll
    for (int j = 0; j < 8; ++j) {
        const float d  = (float)(quad * 8 + j);
        const float th = fn * __expf(-0.28782313662425572f * d);  // n * 10000^(-d/32)
        sn[j] = __sinf(th); cn[j] = __cosf(th);
    }

    // ---- q: load -> RoPE -> exp -> sum -> scale -> bf16 frag (then all dead) ----
    bf16x8 qbh[2];
    {
        bf16x8 q0 = *(const bf16x8*)(Yt + m * 192 +      quad * 8);
        bf16x8 q1 = *(const bf16x8*)(Yt + m * 192 + 32 + quad * 8);
        float e0[8], e1[8], ls = 0.f;
        #pragma unroll
        for (int j = 0; j < 8; ++j) {
            float a0 = (float)q0[j], a1 = (float)q1[j];
            e0[j] = __expf(a0 * cn[j] - a1 * sn[j]);
            e1[j] = __expf(a1 * cn[j] + a0 * sn[j]);
            ls += e0[j] + e1[j];
        }
        ls += __shfl_xor(ls, 16);
        ls += __shfl_xor(ls, 32);
        const float qinv = 0.125f * __builtin_amdgcn_rcpf(ls);
        #pragma unroll
        for (int j = 0; j < 8; ++j) {
            qbh[0][j] = to_bf(e0[j] * qinv);
            qbh[1][j] = to_bf(e1[j] * qinv);
        }
    }

    // ---- k: load -> RoPE -> exp -> butterfly-sum over h -> bf16 frag ----
    bf16x8 kbh[2];
    {
        bf16x8 k0 = *(const bf16x8*)(Yt + m * 192 + 64 + quad * 8);
        bf16x8 k1 = *(const bf16x8*)(Yt + m * 192 + 96 + quad * 8);
        float e0[8], e1[8], c0[8], c1[8];
        #pragma unroll
        for (int j = 0; j < 8; ++j) {
            float a0 = (float)k0[j], a1 = (float)k1[j];
            e0[j] = __expf(a0 * cn[j] - a1 * sn[j]);
            e1[j] = __expf(a1 * cn[j] + a0 * sn[j]);
            c0[j] = e0[j]; c1[j] = e1[j];
        }
        #pragma unroll
        for (int msk = 1; msk <= 8; msk <<= 1)
            #pragma unroll
            for (int j = 0; j < 8; ++j) {
                c0[j] += __shfl_xor(c0[j], msk);
                c1[j] += __shfl_xor(c1[j], msk);
            }
        #pragma unroll
        for (int j = 0; j < 8; ++j) {
            kbh[0][j] = to_bf(e0[j] * __builtin_amdgcn_rcpf(c0[j]));
            kbh[1][j] = to_bf(e1[j] * __builtin_amdgcn_rcpf(c1[j]));
        }
    }

    // ---- S' = k · q^T (C-layout row=h'=quad*4+r, col=h=m) ----
    f32x4 Sp = {0.f, 0.f, 0.f, 0.f};
    Sp = __builtin_amdgcn_mfma_f32_16x16x32_bf16(kbh[0], qbh[0], Sp, 0, 0, 0);
    Sp = __builtin_amdgcn_mfma_f32_16x16x32_bf16(kbh[1], qbh[1], Sp, 0, 0, 0);

    __syncthreads();   // drain v DMA before LDS picks

    f32x4 o4[4];
#if __has_builtin(__builtin_amdgcn_mfma_f32_16x16x16f16)
    // A-frag 16x16x16: A[m][k=quad*4+j] := Sp reg j = S[m][quad*4+j]
    f16x4 af;
    #pragma unroll
    for (int r = 0; r < 4; ++r) af[r] = (_Float16)Sp[r];
    #pragma unroll
    for (int tile = 0; tile < 4; ++tile) {
        f16x4 bv;
        #pragma unroll
        for (int j = 0; j < 4; ++j)
            bv[j] = (_Float16)(float)sm.v[wave][(quad * 4 + j) * 64 + tile * 16 + m];
        f32x4 z = {0.f, 0.f, 0.f, 0.f};
        o4[tile] = __builtin_amdgcn_mfma_f32_16x16x16f16(af, bv, z, 0, 0, 0);
    }
#else
    bf16x8 a2;
    #pragma unroll
    for (int j = 0; j < 8; ++j) {
        int k = quad * 8 + j;
        int src = ((k & 15) >> 2) * 16 + m;
        float v = __shfl(Sp[k & 3], src, 64);
        a2[j] = (quad < 2) ? to_bf(v) : to_bf(0.f);
    }
    #pragma unroll
    for (int tile = 0; tile < 4; ++tile) {
        bf16x8 bv;
        #pragma unroll
        for (int j = 0; j < 8; ++j) {
            int k = quad * 8 + j;
            int kk = (k < 16) ? k : 0;
            bv[j] = sm.v[wave][kk * 64 + tile * 16 + m];
        }
        f32x4 z = {0.f, 0.f, 0.f, 0.f};
        o4[tile] = __builtin_amdgcn_mfma_f32_16x16x32_bf16(a2, bv, z, 0, 0, 0);
    }
#endif

    __syncthreads();   // v dead; reuse LDS as ost

    // ---- stage o row-strips: o[h=quad*4+r][e=tile*16+m] is Ot row s=m*16+quad*4+r,
    //      token-local slot = wave; phys slot XOR-swizzled by s>>4 (=m).
    #pragma unroll
    for (int r = 0; r < 4; ++r) {
        const int s = m * 16 + quad * 4 + r;
        const int phys = (wave + m) & 7;
        ushort4 u;
        u.x = fbits(o4[0][r]); u.y = fbits(o4[1][r]);
        u.z = fbits(o4[2][r]); u.w = fbits(o4[3][r]);
        sm.ost[s][phys] = u;
    }
    __syncthreads();

    // ---- coalesced store: thread -> (row = tid>>1, 32B half (tid&1)) ----
    {
        const int row  = tid >> 1;
        const int half = tid & 1;
        ushort4 u4[4];
        #pragma unroll
        for (int jj = 0; jj < 4; ++jj) {
            const int j = half * 4 + jj;
            const int phys = (j + (row >> 4)) & 7;
            u4[jj] = sm.ost[row][phys];
        }
        __bf16* dst = Ot + (((size_t)(bb * 256 + row)) << 10) + (n0 + half * 4) * 4;
        u16x8 a = {u4[0].x, u4[0].y, u4[0].z, u4[0].w, u4[1].x, u4[1].y, u4[1].z, u4[1].w};
        u16x8 b = {u4[2].x, u4[2].y, u4[2].z, u4[2].w, u4[3].x, u4[3].y, u4[3].z, u4[3].w};
        *(u16x8*)dst = a;
        *(u16x8*)(dst + 8) = b;
    }
}

// ---------------------------------------------------------------------------
extern "C" void kernel_launch(void* const* d_in, const int* in_sizes, int n_in,
                              void* d_out, int out_size, void* d_ws, size_t ws_size,
                              hipStream_t stream) {
    const float* x     = (const float*)d_in[0];
    const float* w_qkv = (const float*)d_in[1];
    const float* w_lin = (const float*)d_in[2];
    const float* b_lin = (const float*)d_in[3];
    float* out = (float*)d_out;

    char* ws = (char*)d_ws;
    __bf16* Y    = (__bf16*)ws;                               // 96 MiB [16384,3072]
    __bf16* XtOt = (__bf16*)(ws + (size_t)100663296);         // 32 MiB [16384,1024] (Xt then Ot)
    __bf16* Wqb  = (__bf16*)(ws + (size_t)134217728);         // 6 MiB  [3072,1024]
    __bf16* Wlb  = (__bf16*)(ws + (size_t)140509184);         // 2 MiB  [1024,1024]

    cvt_w<<<4096, 256, 0, stream>>>(w_qkv, Wqb, w_lin, Wlb);
    xpose_x<<<dim3(8, 32, 64), 256, 0, stream>>>(x, XtOt);

    mfma_gemm<0><<<dim3(128, 24), 256, 0, stream>>>(XtOt, Wqb, (void*)Y, nullptr);
    attn_mfma<<<2048, 512, 0, stream>>>(Y, XtOt);             // Xt dead; reuse as Ot
    mfma_gemm<1><<<dim3(8, 128), 256, 0, stream>>>(Wlb, XtOt, (void*)out, b_lin);
}